// Round 20
// baseline (47.115 us; speedup 1.0000x reference)
//
#include <hip/hip_runtime.h>
#include <math.h>

#define TOKENS 16384
#define HID    2048

typedef float f4 __attribute__((ext_vector_type(4)));
typedef short s8v __attribute__((ext_vector_type(8)));

// shared ws layout:
//   w1   [0, 256KB)   bf16 plane1 [64][2048]  (dead after k_main -> bp reuses)
//   w2   [256KB, 512KB) bf16 plane2
//   part [512KB, ...) fp32 [KSPLIT][16384][64]
//   bp   [0, 128KB)   (reuse of w1 region, written by k_finish)
#define WS_W2   262144
#define WS_PART 524288

__device__ __forceinline__ unsigned short bf16rne(float x) {
  unsigned u = __float_as_uint(x);
  return (unsigned short)((u + 0x7FFFu + ((u >> 16) & 1u)) >> 16);
}

__device__ __forceinline__ void gl16(const void* g, const void* l) {
  __builtin_amdgcn_global_load_lds(
      (const __attribute__((address_space(1))) void*)g,
      (__attribute__((address_space(3))) void*)l, 16, 0, 0);
}

#define BARK(N) { asm volatile("s_waitcnt vmcnt(" #N ") lgkmcnt(0)" ::: "memory"); \
  __builtin_amdgcn_sched_barrier(0); __builtin_amdgcn_s_barrier(); \
  __builtin_amdgcn_sched_barrier(0); }

// fp32 weights -> two bf16 planes (w ~= w1 + w2, residual ~2^-18)
__global__ __launch_bounds__(256) void k_pack(const float* __restrict__ gw,
                                              unsigned short* __restrict__ w1,
                                              unsigned short* __restrict__ w2) {
  int gid = blockIdx.x * 256 + threadIdx.x;
  int m = gid * 8;
  f4 a = *(const f4*)(gw + m);
  f4 b = *(const f4*)(gw + m + 4);
  float av[8] = {a.x, a.y, a.z, a.w, b.x, b.y, b.z, b.w};
  unsigned short p1[8], p2[8];
  #pragma unroll
  for (int i = 0; i < 8; ++i) {
    unsigned short h = bf16rne(av[i]);
    p1[i] = h;
    float r = av[i] - __uint_as_float((unsigned)h << 16);
    p2[i] = bf16rne(r);
  }
  *(s8v*)(w1 + m) = *(s8v*)p1;
  *(s8v*)(w2 + m) = *(s8v*)p2;
}

// ======================= 2-split path (R19, proven) =======================
__global__ __launch_bounds__(512, 1) void k_main2(const float* __restrict__ hid,
                                                  const unsigned short* __restrict__ w1,
                                                  const unsigned short* __restrict__ w2,
                                                  float* __restrict__ part) {
  __shared__ __align__(16) char lds[147456];
  const int tid = threadIdx.x, wave = tid >> 6, lane = tid & 63;
  const int l15 = lane & 15, ks = lane >> 4;
  const int tg = blockIdx.x >> 1, kq = blockIdx.x & 1;
  const int tok0 = tg * 128;

  const char* hb = (const char*)hid;
  size_t asrc[4]; int adst[4];
  #pragma unroll
  for (int j = 0; j < 4; ++j) {
    int u = j * 512 + tid;
    int row = u >> 4, g = u & 15;
    asrc[j] = (size_t)(tok0 + row) * 8192 + (size_t)kq * 4096
            + (size_t)((g ^ (row & 3)) << 4);
    adst[j] = u * 16;
  }
  const char* wpb = (tid < 256) ? (const char*)w1 : (const char*)w2;
  const int bdst0 = (tid < 256) ? 32768 : 40960;
  const int tt = tid & 255;
  size_t bsrc[2]; int bdst[2];
  #pragma unroll
  for (int j = 0; j < 2; ++j) {
    int v = j * 256 + tt;
    int e = v >> 3, g = v & 7;
    bsrc[j] = (size_t)e * 4096 + (size_t)kq * 2048 + (size_t)((g ^ (e & 3)) << 4);
    bdst[j] = bdst0 + v * 16;
  }

  f4 acc[4] = {{0.f,0.f,0.f,0.f},{0.f,0.f,0.f,0.f},{0.f,0.f,0.f,0.f},{0.f,0.f,0.f,0.f}};
  const int arow = wave * 16 + l15, asw = arow & 3;

  auto stage = [&](int c, int bufb) {
    #pragma unroll
    for (int j = 0; j < 4; ++j)
      gl16(hb + asrc[j] + (size_t)c * 256, lds + bufb + adst[j]);
    #pragma unroll
    for (int j = 0; j < 2; ++j)
      gl16(wpb + bsrc[j] + (size_t)c * 128, lds + bufb + bdst[j]);
  };
  auto compute = [&](int bufb) {
    #pragma unroll
    for (int s = 0; s < 2; ++s) {
      int g0 = (s * 8 + ks * 2) ^ asw;
      int g1 = (s * 8 + ks * 2 + 1) ^ asw;
      f4 a0 = *(const f4*)(lds + bufb + arow * 256 + g0 * 16);
      f4 a1 = *(const f4*)(lds + bufb + arow * 256 + g1 * 16);
      float av[8] = {a0.x, a0.y, a0.z, a0.w, a1.x, a1.y, a1.z, a1.w};
      unsigned short p1[8], p2[8];
      #pragma unroll
      for (int i = 0; i < 8; ++i) {
        unsigned short h = bf16rne(av[i]);
        p1[i] = h;
        float r = av[i] - __uint_as_float((unsigned)h << 16);
        p2[i] = bf16rne(r);
      }
      s8v af1 = *(s8v*)p1;
      s8v af2 = *(s8v*)p2;
      #pragma unroll
      for (int nj = 0; nj < 4; ++nj) {
        int e = nj * 16 + l15;
        int g = (s * 4 + ks) ^ (e & 3);
        s8v bw1 = *(const s8v*)(lds + bufb + 32768 + e * 128 + g * 16);
        s8v bw2 = *(const s8v*)(lds + bufb + 40960 + e * 128 + g * 16);
        acc[nj] = __builtin_amdgcn_mfma_f32_16x16x32_bf16(af1, bw1, acc[nj], 0, 0, 0);
        acc[nj] = __builtin_amdgcn_mfma_f32_16x16x32_bf16(af1, bw2, acc[nj], 0, 0, 0);
        acc[nj] = __builtin_amdgcn_mfma_f32_16x16x32_bf16(af2, bw1, acc[nj], 0, 0, 0);
      }
    }
  };

  stage(0, 0);
  stage(1, 49152);
  BARK(6);
  for (int c = 0; c < 16; ++c) {
    const int bufb = (c % 3) * 49152;
    if (c + 2 < 16) { stage(c + 2, ((c + 2) % 3) * 49152); compute(bufb); BARK(6); }
    else if (c + 1 < 16) { compute(bufb); BARK(0); }
    else compute(bufb);
  }

  #pragma unroll
  for (int nj = 0; nj < 4; ++nj) {
    int e = nj * 16 + l15;
    #pragma unroll
    for (int r = 0; r < 4; ++r) {
      int tl = wave * 16 + ks * 4 + r;
      part[((size_t)kq * TOKENS + (size_t)(tok0 + tl)) * 64 + e] = acc[nj][r];
    }
  }
}

// ======================= 4-split path (new) =======================
__global__ __launch_bounds__(512, 1) void k_main4(const float* __restrict__ hid,
                                                  const unsigned short* __restrict__ w1,
                                                  const unsigned short* __restrict__ w2,
                                                  float* __restrict__ part) {
  // 3 buffers * 40960B: A fp32 [256 tok][128B] (32KB) + w1 [64 e][64B] (4KB) + w2 (4KB)
  __shared__ __align__(16) char lds[122880];
  const int tid = threadIdx.x, wave = tid >> 6, lane = tid & 63;
  const int l15 = lane & 15, ks = lane >> 4;
  const int tg = blockIdx.x >> 2, kq = blockIdx.x & 3;   // 64 groups x 4 K-quarters
  const int tok0 = tg * 256;

  const char* hb = (const char*)hid;
  size_t asrc[4]; int adst[4];
  #pragma unroll
  for (int j = 0; j < 4; ++j) {
    int u = j * 512 + tid;
    int row = u >> 3, g = u & 7;          // 8 granules (128B) per row per chunk
    asrc[j] = (size_t)(tok0 + row) * 8192 + (size_t)kq * 2048
            + (size_t)((g ^ (row & 3)) << 4);
    adst[j] = u * 16;
  }
  const char* wpb = (tid < 256) ? (const char*)w1 : (const char*)w2;
  const int bdst0 = (tid < 256) ? 32768 : 36864;
  const int tt = tid & 255;
  const int eB = tt >> 2, gB = tt & 3;    // 4 granules (64B) per expert per chunk
  const size_t bsrc = (size_t)eB * 4096 + (size_t)kq * 1024
                    + (size_t)((gB ^ (eB & 3)) << 4);
  const int bdst = bdst0 + tt * 16;

  f4 acc[2][4];
  #pragma unroll
  for (int mi = 0; mi < 2; ++mi)
    #pragma unroll
    for (int nj = 0; nj < 4; ++nj) acc[mi][nj] = (f4){0.f, 0.f, 0.f, 0.f};

  auto stage = [&](int c, int bufb) {
    #pragma unroll
    for (int j = 0; j < 4; ++j)
      gl16(hb + asrc[j] + (size_t)c * 128, lds + bufb + adst[j]);
    gl16(wpb + bsrc + (size_t)c * 64, lds + bufb + bdst);
  };
  auto compute = [&](int bufb) {
    #pragma unroll
    for (int mi = 0; mi < 2; ++mi) {
      const int arow = wave * 32 + mi * 16 + l15, asw = arow & 3;
      int g0 = (ks * 2) ^ asw;
      int g1 = (ks * 2 + 1) ^ asw;
      f4 a0 = *(const f4*)(lds + bufb + arow * 128 + g0 * 16);
      f4 a1 = *(const f4*)(lds + bufb + arow * 128 + g1 * 16);
      float av[8] = {a0.x, a0.y, a0.z, a0.w, a1.x, a1.y, a1.z, a1.w};
      unsigned short p1[8], p2[8];
      #pragma unroll
      for (int i = 0; i < 8; ++i) {
        unsigned short h = bf16rne(av[i]);
        p1[i] = h;
        float r = av[i] - __uint_as_float((unsigned)h << 16);
        p2[i] = bf16rne(r);
      }
      s8v af1 = *(s8v*)p1;
      s8v af2 = *(s8v*)p2;
      #pragma unroll
      for (int nj = 0; nj < 4; ++nj) {
        int e = nj * 16 + l15;
        int g = ks ^ (e & 3);
        s8v bw1 = *(const s8v*)(lds + bufb + 32768 + e * 64 + g * 16);
        s8v bw2 = *(const s8v*)(lds + bufb + 36864 + e * 64 + g * 16);
        acc[mi][nj] = __builtin_amdgcn_mfma_f32_16x16x32_bf16(af1, bw1, acc[mi][nj], 0, 0, 0);
        acc[mi][nj] = __builtin_amdgcn_mfma_f32_16x16x32_bf16(af1, bw2, acc[mi][nj], 0, 0, 0);
        acc[mi][nj] = __builtin_amdgcn_mfma_f32_16x16x32_bf16(af2, bw1, acc[mi][nj], 0, 0, 0);
      }
    }
  };

  stage(0, 0);
  stage(1, 40960);
  BARK(5);
  for (int c = 0; c < 16; ++c) {
    const int bufb = (c % 3) * 40960;
    if (c + 2 < 16) { stage(c + 2, ((c + 2) % 3) * 40960); compute(bufb); BARK(5); }
    else if (c + 1 < 16) { compute(bufb); BARK(0); }
    else compute(bufb);
  }

  #pragma unroll
  for (int mi = 0; mi < 2; ++mi)
    #pragma unroll
    for (int nj = 0; nj < 4; ++nj) {
      int e = nj * 16 + l15;
      #pragma unroll
      for (int r = 0; r < 4; ++r) {
        int tl = wave * 32 + mi * 16 + ks * 4 + r;
        part[((size_t)kq * TOKENS + (size_t)(tok0 + tl)) * 64 + e] = acc[mi][nj][r];
      }
    }
}

// k_finish: sum NS K-slices, softmax/top-2, aux partials via LDS transpose
template <int NS>
__global__ __launch_bounds__(64) void k_finish(const float* __restrict__ part,
                                               float* __restrict__ out,
                                               float* __restrict__ bp) {
  __shared__ float pr[64][65];
  __shared__ float cnt[64];
  const int lane = threadIdx.x;
  const int t = blockIdx.x * 64 + lane;

  cnt[lane] = 0.f;

  float lg[64];
  #pragma unroll
  for (int e = 0; e < 64; e += 4) {
    f4 s0 = *(const f4*)(part + (size_t)t * 64 + e);
    #pragma unroll
    for (int q = 1; q < NS; ++q) {
      f4 sq = *(const f4*)(part + (size_t)q * TOKENS * 64 + (size_t)t * 64 + e);
      s0.x += sq.x; s0.y += sq.y; s0.z += sq.z; s0.w += sq.w;
    }
    lg[e] = s0.x; lg[e + 1] = s0.y; lg[e + 2] = s0.z; lg[e + 3] = s0.w;
  }

  float m = lg[0];
  #pragma unroll
  for (int e = 1; e < 64; ++e) m = fmaxf(m, lg[e]);
  float s = 0.f;
  #pragma unroll
  for (int e = 0; e < 64; ++e) { lg[e] = __expf(lg[e] - m); s += lg[e]; }
  const float inv = 1.f / s;

  float b0 = -1.f, b1 = -1.f;
  int i0 = 0, i1 = 0;
  #pragma unroll
  for (int e = 0; e < 64; ++e) {
    float p = lg[e];
    if (p > b0)      { b1 = b0; i1 = i0; b0 = p; i0 = e; }
    else if (p > b1) { b1 = p; i1 = e; }
  }
  const float rs = 1.f / (b0 + b1);
  out[(size_t)t * 2]                  = b0 * rs;
  out[(size_t)t * 2 + 1]              = b1 * rs;
  out[(size_t)TOKENS * 2 + t * 2]     = (float)i0;
  out[(size_t)TOKENS * 2 + t * 2 + 1] = (float)i1;

  #pragma unroll
  for (int e = 0; e < 64; ++e) pr[lane][e] = lg[e] * inv;
  atomicAdd(&cnt[i0], 1.f);
  atomicAdd(&cnt[i1], 1.f);
  __syncthreads();

  float sp = 0.f;
  #pragma unroll 8
  for (int tt = 0; tt < 64; ++tt) sp += pr[tt][lane];
  bp[(size_t)blockIdx.x * 128 + lane]      = sp;
  bp[(size_t)blockIdx.x * 128 + 64 + lane] = cnt[lane];
}

__global__ __launch_bounds__(1024) void k_loss(const float* __restrict__ bp,
                                               float* __restrict__ out) {
  __shared__ float partial[8][128];
  const int tid = threadIdx.x;
  const int col = tid & 127, grp = tid >> 7;
  float s = 0.f;
  #pragma unroll 4
  for (int j = 0; j < 32; ++j)
    s += bp[(size_t)(grp + j * 8) * 128 + col];
  partial[grp][col] = s;
  __syncthreads();
  if (tid < 128) {
    float t = 0.f;
    #pragma unroll
    for (int g = 0; g < 8; ++g) t += partial[g][tid];
    partial[0][tid] = t;
  }
  __syncthreads();
  if (tid < 64) {
    float v = partial[0][tid] * partial[0][64 + tid];
    #pragma unroll
    for (int d = 1; d < 64; d <<= 1) v += __shfl_xor(v, d);
    if (tid == 0)
      out[(size_t)TOKENS * 4] = 0.01f * 64.f * v / (16384.f * 16384.f);
  }
}

extern "C" void kernel_launch(void* const* d_in, const int* in_sizes, int n_in,
                              void* d_out, int out_size, void* d_ws, size_t ws_size,
                              hipStream_t stream) {
  (void)in_sizes; (void)n_in; (void)out_size;
  const float* hid = (const float*)d_in[0];
  const float* gw  = (const float*)d_in[1];
  float* out = (float*)d_out;
  char* ws = (char*)d_ws;
  unsigned short* w1 = (unsigned short*)ws;            // dead after k_main
  unsigned short* w2 = (unsigned short*)(ws + WS_W2);  // dead after k_main
  float* part  = (float*)(ws + WS_PART);
  float* bp    = (float*)ws;                           // reuses w1 region

  const size_t NEED4 = (size_t)WS_PART + (size_t)4 * TOKENS * 64 * 4;  // ~17.3 MB

  k_pack<<<64, 256, 0, stream>>>(gw, w1, w2);
  if (ws_size >= NEED4) {
    k_main4   <<<256, 512, 0, stream>>>(hid, w1, w2, part);
    k_finish<4><<<256, 64, 0, stream>>>(part, out, bp);
  } else {
    k_main2   <<<256, 512, 0, stream>>>(hid, w1, w2, part);
    k_finish<2><<<256, 64, 0, stream>>>(part, out, bp);
  }
  k_loss<<<1, 1024, 0, stream>>>(bp, out);
}

// Round 21
// 45.822 us; speedup vs baseline: 1.0282x; 1.0282x over previous
//
#include <hip/hip_runtime.h>
#include <math.h>

#define TOKENS 16384
#define HID    2048
#define NCH    16
#define TPB    128         // tokens per block-group (2 K-split blocks share it)

typedef float f4 __attribute__((ext_vector_type(4)));
typedef short s8v __attribute__((ext_vector_type(8)));

// ws byte layout:
//   w1   [0, 256KB)          bf16 plane1 [64][2048]   (dead after k_main)
//   w2   [256KB, 512KB)      bf16 plane2 [64][2048]   (dead after k_main)
//   part [512KB, 512KB+8MB)  fp32 [2][16384][64] partial logits
//   bp   [0, 128KB)          reuses w1 region (written by k_finish)
#define WS_W2   262144
#define WS_PART 524288

__device__ __forceinline__ unsigned short bf16rne(float x) {
  unsigned u = __float_as_uint(x);
  return (unsigned short)((u + 0x7FFFu + ((u >> 16) & 1u)) >> 16);
}

__device__ __forceinline__ void gl16(const void* g, const void* l) {
  __builtin_amdgcn_global_load_lds(
      (const __attribute__((address_space(1))) void*)g,
      (__attribute__((address_space(3))) void*)l, 16, 0, 0);
}

#define BARK(N) { asm volatile("s_waitcnt vmcnt(" #N ") lgkmcnt(0)" ::: "memory"); \
  __builtin_amdgcn_sched_barrier(0); __builtin_amdgcn_s_barrier(); \
  __builtin_amdgcn_sched_barrier(0); }

// fp32 weights -> two bf16 planes (w ~= w1 + w2, residual ~2^-18)
__global__ __launch_bounds__(256) void k_pack(const float* __restrict__ gw,
                                              unsigned short* __restrict__ w1,
                                              unsigned short* __restrict__ w2) {
  int gid = blockIdx.x * 256 + threadIdx.x;   // 16384 threads * 8 els
  int m = gid * 8;
  f4 a = *(const f4*)(gw + m);
  f4 b = *(const f4*)(gw + m + 4);
  float av[8] = {a.x, a.y, a.z, a.w, b.x, b.y, b.z, b.w};
  unsigned short p1[8], p2[8];
  #pragma unroll
  for (int i = 0; i < 8; ++i) {
    unsigned short h = bf16rne(av[i]);
    p1[i] = h;
    float r = av[i] - __uint_as_float((unsigned)h << 16);
    p2[i] = bf16rne(r);
  }
  *(s8v*)(w1 + m) = *(s8v*)p1;
  *(s8v*)(w2 + m) = *(s8v*)p2;
}

__global__ __launch_bounds__(512, 1) void k_main(const float* __restrict__ hid,
                                                 const unsigned short* __restrict__ w1,
                                                 const unsigned short* __restrict__ w2,
                                                 float* __restrict__ part) {
  // 3 buffers * 49152B: A fp32 [128 tok][256B] (32KB) + w1 [64 e][128B] (8KB) + w2 (8KB)
  __shared__ __align__(16) char lds[147456];
  const int tid = threadIdx.x, wave = tid >> 6, lane = tid & 63;
  const int l15 = lane & 15, ks = lane >> 4;
  const int tg = blockIdx.x >> 1, kq = blockIdx.x & 1;   // token-group, K-half
  const int tok0 = tg * TPB;

  // ---- staging sources (64B-line-local granule permutation; LDS dest linear) ----
  const char* hb = (const char*)hid;
  size_t asrc[4]; int adst[4];
  #pragma unroll
  for (int j = 0; j < 4; ++j) {
    int u = j * 512 + tid;
    int row = u >> 4, g = u & 15;
    asrc[j] = (size_t)(tok0 + row) * 8192 + (size_t)kq * 4096
            + (size_t)((g ^ (row & 3)) << 4);
    adst[j] = u * 16;
  }
  // B: waves 0-3 stage w1, waves 4-7 stage w2 (2 granules/thread)
  const char* wpb = (tid < 256) ? (const char*)w1 : (const char*)w2;
  const int bdst0 = (tid < 256) ? 32768 : 40960;
  const int tt = tid & 255;
  size_t bsrc[2]; int bdst[2];
  #pragma unroll
  for (int j = 0; j < 2; ++j) {
    int v = j * 256 + tt;
    int e = v >> 3, g = v & 7;
    bsrc[j] = (size_t)e * 4096 + (size_t)kq * 2048 + (size_t)((g ^ (e & 3)) << 4);
    bdst[j] = bdst0 + v * 16;
  }

  f4 acc[4] = {{0.f,0.f,0.f,0.f},{0.f,0.f,0.f,0.f},{0.f,0.f,0.f,0.f},{0.f,0.f,0.f,0.f}};
  const int arow = wave * 16 + l15, asw = arow & 3;

  auto stage = [&](int c, int bufb) {
    #pragma unroll
    for (int j = 0; j < 4; ++j)
      gl16(hb + asrc[j] + (size_t)c * 256, lds + bufb + adst[j]);
    #pragma unroll
    for (int j = 0; j < 2; ++j)
      gl16(wpb + bsrc[j] + (size_t)c * 128, lds + bufb + bdst[j]);
  };

  auto compute = [&](int bufb) {
    #pragma unroll
    for (int s = 0; s < 2; ++s) {
      int g0 = (s * 8 + ks * 2) ^ asw;
      int g1 = (s * 8 + ks * 2 + 1) ^ asw;
      f4 a0 = *(const f4*)(lds + bufb + arow * 256 + g0 * 16);
      f4 a1 = *(const f4*)(lds + bufb + arow * 256 + g1 * 16);
      float av[8] = {a0.x, a0.y, a0.z, a0.w, a1.x, a1.y, a1.z, a1.w};
      unsigned short p1[8], p2[8];
      #pragma unroll
      for (int i = 0; i < 8; ++i) {
        unsigned short h = bf16rne(av[i]);
        p1[i] = h;
        float r = av[i] - __uint_as_float((unsigned)h << 16);
        p2[i] = bf16rne(r);
      }
      s8v af1 = *(s8v*)p1;
      s8v af2 = *(s8v*)p2;
      #pragma unroll
      for (int nj = 0; nj < 4; ++nj) {
        int e = nj * 16 + l15;
        int g = (s * 4 + ks) ^ (e & 3);
        s8v bw1 = *(const s8v*)(lds + bufb + 32768 + e * 128 + g * 16);
        s8v bw2 = *(const s8v*)(lds + bufb + 40960 + e * 128 + g * 16);
        acc[nj] = __builtin_amdgcn_mfma_f32_16x16x32_bf16(af1, bw1, acc[nj], 0, 0, 0);
        acc[nj] = __builtin_amdgcn_mfma_f32_16x16x32_bf16(af1, bw2, acc[nj], 0, 0, 0);
        acc[nj] = __builtin_amdgcn_mfma_f32_16x16x32_bf16(af2, bw1, acc[nj], 0, 0, 0);
      }
    }
  };

  stage(0, 0);
  stage(1, 49152);
  BARK(6);

  for (int c = 0; c < NCH; ++c) {
    const int bufb = (c % 3) * 49152;
    if (c + 2 < NCH) {
      stage(c + 2, ((c + 2) % 3) * 49152);
      compute(bufb);
      BARK(6);
    } else if (c + 1 < NCH) {
      compute(bufb);
      BARK(0);
    } else {
      compute(bufb);
    }
  }

  // ---- write partial logits: part[kq][token][expert] ----
  #pragma unroll
  for (int nj = 0; nj < 4; ++nj) {
    int e = nj * 16 + l15;
    #pragma unroll
    for (int r = 0; r < 4; ++r) {
      int tl = wave * 16 + ks * 4 + r;
      part[((size_t)kq * TOKENS + (size_t)(tok0 + tl)) * 64 + e] = acc[nj][r];
    }
  }
}

// sum the two K-halves, softmax/top-2; aux partials via LDS transpose
__global__ __launch_bounds__(64) void k_finish(const float* __restrict__ part,
                                               float* __restrict__ out,
                                               float* __restrict__ bp) {
  __shared__ float pr[64][65];   // [token][expert], stride 65 -> conflict-free
  __shared__ float cnt[64];
  const int lane = threadIdx.x;
  const int t = blockIdx.x * 64 + lane;

  cnt[lane] = 0.f;

  float lg[64];
  const float* p0 = part + (size_t)t * 64;
  const float* p1 = part + (size_t)TOKENS * 64 + (size_t)t * 64;
  #pragma unroll
  for (int e = 0; e < 64; e += 4) {
    f4 a = *(const f4*)(p0 + e);
    f4 b = *(const f4*)(p1 + e);
    lg[e]     = a.x + b.x;
    lg[e + 1] = a.y + b.y;
    lg[e + 2] = a.z + b.z;
    lg[e + 3] = a.w + b.w;
  }

  float m = lg[0];
  #pragma unroll
  for (int e = 1; e < 64; ++e) m = fmaxf(m, lg[e]);
  float s = 0.f;
  #pragma unroll
  for (int e = 0; e < 64; ++e) { lg[e] = __expf(lg[e] - m); s += lg[e]; }
  const float inv = 1.f / s;

  // top-2 on exp values (monotone); strict '>' == lax.top_k tie-break
  float b0 = -1.f, b1 = -1.f;
  int i0 = 0, i1 = 0;
  #pragma unroll
  for (int e = 0; e < 64; ++e) {
    float p = lg[e];
    if (p > b0)      { b1 = b0; i1 = i0; b0 = p; i0 = e; }
    else if (p > b1) { b1 = p; i1 = e; }
  }
  const float rs = 1.f / (b0 + b1);
  out[(size_t)t * 2]                  = b0 * rs;
  out[(size_t)t * 2 + 1]              = b1 * rs;
  out[(size_t)TOKENS * 2 + t * 2]     = (float)i0;
  out[(size_t)TOKENS * 2 + t * 2 + 1] = (float)i1;

  // aux partials: write softmax probs row, count top-2 via LDS atomics
  #pragma unroll
  for (int e = 0; e < 64; ++e) pr[lane][e] = lg[e] * inv;
  atomicAdd(&cnt[i0], 1.f);
  atomicAdd(&cnt[i1], 1.f);
  __syncthreads();

  float sp = 0.f;
  #pragma unroll 8
  for (int tt = 0; tt < 64; ++tt) sp += pr[tt][lane];   // expert-column sum
  bp[(size_t)blockIdx.x * 128 + lane]      = sp;
  bp[(size_t)blockIdx.x * 128 + 64 + lane] = cnt[lane];
}

// fused loss reduction: one block, 1024 threads, parallel strided loads
__global__ __launch_bounds__(1024) void k_loss(const float* __restrict__ bp,
                                               float* __restrict__ out) {
  __shared__ float partial[8][128];
  const int tid = threadIdx.x;
  const int col = tid & 127, grp = tid >> 7;   // 8 groups x 128 cols
  float s = 0.f;
  #pragma unroll 4
  for (int j = 0; j < 32; ++j)
    s += bp[(size_t)(grp + j * 8) * 128 + col];
  partial[grp][col] = s;
  __syncthreads();
  if (tid < 128) {
    float t = 0.f;
    #pragma unroll
    for (int g = 0; g < 8; ++g) t += partial[g][tid];
    partial[0][tid] = t;
  }
  __syncthreads();
  if (tid < 64) {
    float v = partial[0][tid] * partial[0][64 + tid];   // sumprob_e * count_e
    #pragma unroll
    for (int d = 1; d < 64; d <<= 1) v += __shfl_xor(v, d);
    if (tid == 0)
      out[(size_t)TOKENS * 4] = 0.01f * 64.f * v / (16384.f * 16384.f);
  }
}

extern "C" void kernel_launch(void* const* d_in, const int* in_sizes, int n_in,
                              void* d_out, int out_size, void* d_ws, size_t ws_size,
                              hipStream_t stream) {
  (void)in_sizes; (void)n_in; (void)out_size; (void)ws_size;
  const float* hid = (const float*)d_in[0];
  const float* gw  = (const float*)d_in[1];
  float* out = (float*)d_out;
  char* ws = (char*)d_ws;
  unsigned short* w1 = (unsigned short*)ws;            // dead after k_main
  unsigned short* w2 = (unsigned short*)(ws + WS_W2);  // dead after k_main
  float* part  = (float*)(ws + WS_PART);
  float* bp    = (float*)ws;                           // reuses w1 region

  k_pack  <<<64, 256, 0, stream>>>(gw, w1, w2);
  k_main  <<<256, 512, 0, stream>>>(hid, w1, w2, part);
  k_finish<<<256, 64, 0, stream>>>(part, out, bp);
  k_loss  <<<1, 1024, 0, stream>>>(bp, out);
}